// Round 2
// baseline (120611.633 us; speedup 1.0000x reference)
//
#include <hip/hip_runtime.h>
#include <math.h>

#define TID ((int)threadIdx.x)

namespace {

constexpr int Bn = 256, Tn = 256, Dn = 256, Hn = 512, Sn = 32;
constexpr int BC = 128;                 // batch rows per team
constexpr int XP = 268;                 // X pair-row stride (floats): row = 2 k-values interleaved
constexpr int CHF = 16 * XP;            // floats per 32-k chunk buffer (4288)
constexpr int BTS = Bn * Tn * Sn;
constexpr int OFF_ST = 0, OFF_PRM = BTS, OFF_PRLV = 2 * BTS, OFF_PM = 3 * BTS,
              OFF_PLV = 4 * BTS, OFF_HF = 5 * BTS;

// LDS float offsets
constexpr int oWH0 = 0;                  // whh0^T [512][12]
constexpr int oWH1 = oWH0 + 512 * 12;    // whh1^T
constexpr int oWI1 = oWH1 + 512 * 12;    // wih1^T
constexpr int oWI0 = oWI1 + 512 * 12;    // wih0^T [288][12]
constexpr int oWP1 = oWI0 + 288 * 12;    // wpost1^T [768][4]
constexpr int oWQ1 = oWP1 + 768 * 4;     // wprior1^T [512][4]
constexpr int oWHD = oWQ1 + 512 * 4;     // head row [512]
constexpr int oGA  = oWHD + 512;         // gh0 (+bhh0) [128][12]
constexpr int oGB  = oGA + 128 * 12;     // gh1 (+bhh1)
constexpr int oXT  = oGB + 128 * 12;     // X chunk dbuf: 2 * CHF
constexpr int LDS_FLOATS = oXT + 2 * CHF;            // 39168 floats
constexpr int LDS_BYTES  = LDS_FLOATS * 4;           // 156672 B (< 160 KiB)

struct P {
  const float *latent, *hidden, *eps;
  const float *wih0, *whh0, *bih0, *bhh0;
  const float *wih1, *whh1, *bih1, *bhh1;
  const float *wpost1, *bpost1, *wpost2, *bpost2;
  const float *wprior1, *bprior1, *wprior2, *bprior2;
  float *out;
  float *h0, *h1, *ph, *qh, *ppv;   // ws views (fp32)
  unsigned *bars;                   // leaf[2][8], root[2], rel[2]
};

struct F4x2 { float4 a, b; };
struct SR { float4 pm0, pm1, lv0, lv1, e0, e1; };

// ---------- two-level monotonic team barrier (128 blocks / team) ----------
__device__ __forceinline__ void team_bar(const P& p, int bg, int grp, int e) {
  __syncthreads();
  if (TID == 0) {
    unsigned* leaf = p.bars + bg * 8 + grp;
    unsigned* root = p.bars + 16 + bg;
    unsigned* rel  = p.bars + 18 + bg;
    unsigned old = __hip_atomic_fetch_add(leaf, 1u, __ATOMIC_RELEASE, __HIP_MEMORY_SCOPE_AGENT);
    if ((old & 15u) == 15u) {
      unsigned r = __hip_atomic_fetch_add(root, 1u, __ATOMIC_ACQ_REL, __HIP_MEMORY_SCOPE_AGENT);
      if ((r & 7u) == 7u)
        __hip_atomic_store(rel, (unsigned)e, __ATOMIC_RELEASE, __HIP_MEMORY_SCOPE_AGENT);
    }
    while (__hip_atomic_load(rel, __ATOMIC_RELAXED, __HIP_MEMORY_SCOPE_AGENT) < (unsigned)e)
      __builtin_amdgcn_s_sleep(2);
    (void)__hip_atomic_load(rel, __ATOMIC_ACQUIRE, __HIP_MEMORY_SCOPE_AGENT);
  }
  __syncthreads();
}

// ---------- weight preload (transpose into LDS, once) ----------
template<int K>
__device__ void preload12(float* wt, const float* __restrict__ W, int os) {
  constexpr int KQ = K / 4;
  for (int u = TID; u < 12 * KQ; u += 512) {
    int c = u / KQ, kq = u - c * KQ;
    int row = (c >> 2) * Hn + os * 4 + (c & 3);
    float4 w = *(const float4*)(W + (size_t)row * K + kq * 4);
    int k = kq * 4;
    wt[(k + 0) * 12 + c] = w.x; wt[(k + 1) * 12 + c] = w.y;
    wt[(k + 2) * 12 + c] = w.z; wt[(k + 3) * 12 + c] = w.w;
  }
}
template<int K>
__device__ void preload4(float* wt, const float* __restrict__ W, int os) {
  constexpr int KQ = K / 4;
  for (int u = TID; u < 4 * KQ; u += 512) {
    int c = u / KQ, kq = u - c * KQ;
    int row = os * 4 + c;
    float4 w = *(const float4*)(W + (size_t)row * K + kq * 4);
    int k = kq * 4;
    wt[(k + 0) * 4 + c] = w.x; wt[(k + 1) * 4 + c] = w.y;
    wt[(k + 2) * 4 + c] = w.z; wt[(k + 3) * 4 + c] = w.w;
  }
}

// ---------- activation staging ----------
__device__ __forceinline__ F4x2 stLoad(const float* __restrict__ src, size_t ld, int k0) {
  F4x2 v;
  const int r0 = TID >> 3, kq = TID & 7;
  v.a = *(const float4*)(src + (size_t)r0 * ld + k0 + kq * 4);
  v.b = *(const float4*)(src + (size_t)(r0 + 64) * ld + k0 + kq * 4);
  return v;
}
__device__ __forceinline__ void stWrite(float* __restrict__ xb, const F4x2& v) {
  const int r0 = TID >> 3, kq = TID & 7;
  *(float2*)&xb[(2 * kq) * XP + 2 * r0]       = make_float2(v.a.x, v.a.y);
  *(float2*)&xb[(2 * kq + 1) * XP + 2 * r0]   = make_float2(v.a.z, v.a.w);
  *(float2*)&xb[(2 * kq) * XP + 2 * (r0 + 64)]     = make_float2(v.b.x, v.b.y);
  *(float2*)&xb[(2 * kq + 1) * XP + 2 * (r0 + 64)] = make_float2(v.b.z, v.b.w);
}

// ---------- compute tiles ----------
__device__ __forceinline__ void mm12(float* __restrict__ acc, const float* __restrict__ xb,
                                     const float* __restrict__ wt, int rp, int ks) {
  const float4 xa = *(const float4*)&xb[ks * XP + rp * 8];
  const float4 xc = *(const float4*)&xb[ks * XP + rp * 8 + 4];
  const float* w = wt + ks * 24;
  float wA[12], wB[12];
  #pragma unroll
  for (int c = 0; c < 12; c += 4) {
    *(float4*)&wA[c] = *(const float4*)&w[c];
    *(float4*)&wB[c] = *(const float4*)&w[12 + c];
  }
  const float x0[4] = {xa.x, xa.z, xc.x, xc.z};
  const float x1[4] = {xa.y, xa.w, xc.y, xc.w};
  #pragma unroll
  for (int ri = 0; ri < 4; ri++)
    #pragma unroll
    for (int c = 0; c < 12; c++)
      acc[ri * 12 + c] += x0[ri] * wA[c] + x1[ri] * wB[c];
}

template<bool DP>
__device__ __forceinline__ void mmE(float* __restrict__ acc, const float* __restrict__ xb,
                                    const float* __restrict__ wq, const float* __restrict__ wp,
                                    int rp, int ks) {
  const float4 xa = *(const float4*)&xb[ks * XP + rp * 8];
  const float4 xc = *(const float4*)&xb[ks * XP + rp * 8 + 4];
  const float x0[4] = {xa.x, xa.z, xc.x, xc.z};
  const float x1[4] = {xa.y, xa.w, xc.y, xc.w};
  const float4 q0 = *(const float4*)&wq[ks * 8];
  const float4 q1 = *(const float4*)&wq[ks * 8 + 4];
  const float qA[4] = {q0.x, q0.y, q0.z, q0.w};
  const float qB[4] = {q1.x, q1.y, q1.z, q1.w};
  float pA[4] = {0, 0, 0, 0}, pB[4] = {0, 0, 0, 0};
  if (DP) {
    const float4 p0 = *(const float4*)&wp[ks * 8];
    const float4 p1 = *(const float4*)&wp[ks * 8 + 4];
    pA[0] = p0.x; pA[1] = p0.y; pA[2] = p0.z; pA[3] = p0.w;
    pB[0] = p1.x; pB[1] = p1.y; pB[2] = p1.z; pB[3] = p1.w;
  }
  #pragma unroll
  for (int ri = 0; ri < 4; ri++)
    #pragma unroll
    for (int c = 0; c < 4; c++) {
      acc[ri * 8 + c] += x0[ri] * qA[c] + x1[ri] * qB[c];
      if (DP) acc[ri * 8 + 4 + c] += x0[ri] * pA[c] + x1[ri] * pB[c];
    }
}

__device__ __forceinline__ void mmEpost(float* __restrict__ acc, const float* __restrict__ xb,
                                        const float* __restrict__ wp, int rp, int ks) {
  const float4 xa = *(const float4*)&xb[ks * XP + rp * 8];
  const float4 xc = *(const float4*)&xb[ks * XP + rp * 8 + 4];
  const float x0[4] = {xa.x, xa.z, xc.x, xc.z};
  const float x1[4] = {xa.y, xa.w, xc.y, xc.w};
  const float4 p0 = *(const float4*)&wp[ks * 8];
  const float4 p1 = *(const float4*)&wp[ks * 8 + 4];
  const float pA[4] = {p0.x, p0.y, p0.z, p0.w};
  const float pB[4] = {p1.x, p1.y, p1.z, p1.w};
  #pragma unroll
  for (int ri = 0; ri < 4; ri++)
    #pragma unroll
    for (int c = 0; c < 4; c++)
      acc[ri * 8 + 4 + c] += x0[ri] * pA[c] + x1[ri] * pB[c];
}

template<int N>
__device__ __forceinline__ void bfly(float* acc) {
  #pragma unroll
  for (int m = 1; m <= 8; m <<= 1)
    #pragma unroll
    for (int i = 0; i < N; i++)
      acc[i] += __shfl_xor(acc[i], m, 64);
}

__global__ __launch_bounds__(512, 2) void rssm_kernel(P p) {
  extern __shared__ float sm[];
  const int bg = blockIdx.x & 1;        // team
  const int os = blockIdx.x >> 1;       // H-slice 0..127 (4 cols)
  const int grp = os & 7;
  const int rp = TID >> 4, ks = TID & 15;
  int ep = 0;

  float* WH0 = sm + oWH0; float* WH1 = sm + oWH1; float* WI1 = sm + oWI1;
  float* WI0 = sm + oWI0; float* WP1 = sm + oWP1; float* WQ1 = sm + oWQ1;
  float* WHD = sm + oWHD; float* GA = sm + oGA;  float* GB = sm + oGB;
  auto XT = [&](int i) { return sm + oXT + i * CHF; };

  // ---- one-time weight preload ----
  preload12<512>(WH0, p.whh0, os);
  preload12<512>(WH1, p.whh1, os);
  preload12<512>(WI1, p.wih1, os);
  preload12<288>(WI0, p.wih0, os);
  preload4<768>(WP1, p.wpost1, os);
  preload4<512>(WQ1, p.wprior1, os);
  {
    const float* hw = (os < 64) ? (p.wpost2 + (size_t)os * Hn)
                                : (p.wprior2 + (size_t)(os - 64) * Hn);
    for (int u = TID; u < 128; u += 512)
      *(float4*)&WHD[u * 4] = *(const float4*)(hw + u * 4);
  }
  // ---- prologue: hidden -> h0/h1 (own slice) ----
  {
    const int r = TID >> 2, j = TID & 3;
    const int b = bg * BC + r, col = os * 4 + j;
    p.h0[(size_t)b * Hn + col] = p.hidden[(size_t)b * Hn + col];
    p.h1[(size_t)b * Hn + col] = p.hidden[(size_t)Bn * Hn + b * Hn + col];
  }
  team_bar(p, bg, grp, ++ep);

  // ---- generic 12-col pipeline over nch 32-k chunks ----
  auto runMM12 = [&](float* acc, const float* src, size_t ld, const float* wt, int nch) {
    F4x2 nxt;
    { F4x2 cur = stLoad(src, ld, 0);
      if (nch > 1) nxt = stLoad(src, ld, 32);
      stWrite(XT(0), cur); }
    __syncthreads();
    for (int c = 0; c < nch; c++) {
      F4x2 fut;
      if (c + 2 < nch) fut = stLoad(src, ld, (c + 2) * 32);
      mm12(acc, XT(c & 1), wt + c * 32 * 12, rp, ks);
      if (c + 1 < nch) stWrite(XT((c + 1) & 1), nxt);
      __syncthreads();
      nxt = fut;
    }
  };

  auto writeG = [&](float* G, const float* acc, const float* bhh) {
    if (ks < 12) {
      const int c = ks, g = c >> 2, j = c & 3;
      const float bb = bhh[g * Hn + os * 4 + j];
      #pragma unroll
      for (int i = 0; i < 4; i++) G[(rp * 4 + i) * 12 + c] = acc[i * 12 + c] + bb;
    }
  };

  auto combine = [&](const float* acc, const float* G, float* hbuf, const float* bih) {
    if (ks < 4) {
      const int j = ks, col = os * 4 + j;
      const float b0 = bih[col], b1 = bih[Hn + col], b2 = bih[2 * Hn + col];
      #pragma unroll
      for (int i = 0; i < 4; i++) {
        const int r = rp * 4 + i, b = bg * BC + r;
        const float gr = acc[i * 12 + j] + b0 + G[r * 12 + j];
        const float gz = acc[i * 12 + 4 + j] + b1 + G[r * 12 + 4 + j];
        const float gn = acc[i * 12 + 8 + j] + b2;
        const float hnv = G[r * 12 + 8 + j];
        const float rg = 1.f / (1.f + expf(-gr));
        const float zg = 1.f / (1.f + expf(-gz));
        const float ng = tanhf(gn + rg * hnv);
        const size_t idx = (size_t)b * Hn + col;
        hbuf[idx] = (1.f - zg) * ng + zg * hbuf[idx];
      }
    }
  };

  auto headPhase = [&](int t, bool post) {
    const int r = TID >> 2, kq = TID & 3;
    const int b = bg * BC + r;
    const float* xs = (post ? p.ph : p.qh) + (size_t)b * Hn;
    float d = 0.f;
    #pragma unroll
    for (int q = 0; q < 32; q++) {
      const int k = kq * 128 + q * 4;
      const float4 xv = *(const float4*)(xs + k);
      const float4 wv = *(const float4*)&WHD[k];
      d += xv.x * wv.x + xv.y * wv.y + xv.z * wv.z + xv.w * wv.w;
    }
    d += __shfl_xor(d, 1, 64);
    d += __shfl_xor(d, 2, 64);
    if (kq == 0) {
      if (post) {
        const float val = d + p.bpost2[os];
        p.ppv[(size_t)b * 64 + os] = val;
        const size_t o = ((size_t)b * Tn + t) * Sn + (os & 31);
        p.out[(os < 32 ? OFF_PM : OFF_PLV) + o] = val;
      } else {
        const int cc = os - 64;
        const float val = d + p.bprior2[cc];
        const size_t o = ((size_t)b * Tn + (t - 1)) * Sn + (cc & 31);
        p.out[(cc < 32 ? OFF_PRM : OFF_PRLV) + o] = val;
      }
    }
  };

  auto stochLoad = [&](SR& s, int t) {
    const int r = TID >> 2, sq = TID & 3;
    const int b = bg * BC + r;
    const float* pv = p.ppv + (size_t)b * 64;
    s.pm0 = *(const float4*)(pv + sq * 8);
    s.pm1 = *(const float4*)(pv + sq * 8 + 4);
    s.lv0 = *(const float4*)(pv + 32 + sq * 8);
    s.lv1 = *(const float4*)(pv + 32 + sq * 8 + 4);
    const float* epp = p.eps + ((size_t)b * Tn + t) * Sn + sq * 8;
    s.e0 = *(const float4*)epp;
    s.e1 = *(const float4*)(epp + 4);
  };
  auto stochWrite = [&](float* xb, const SR& s, int t) {
    const int r = TID >> 2, sq = TID & 3;
    const int b = bg * BC + r;
    const float pm[8] = {s.pm0.x, s.pm0.y, s.pm0.z, s.pm0.w, s.pm1.x, s.pm1.y, s.pm1.z, s.pm1.w};
    const float lv[8] = {s.lv0.x, s.lv0.y, s.lv0.z, s.lv0.w, s.lv1.x, s.lv1.y, s.lv1.z, s.lv1.w};
    const float ev[8] = {s.e0.x, s.e0.y, s.e0.z, s.e0.w, s.e1.x, s.e1.y, s.e1.z, s.e1.w};
    float sv[8];
    #pragma unroll
    for (int u = 0; u < 8; u++) sv[u] = pm[u] + ev[u] * expf(0.5f * lv[u]);
    #pragma unroll
    for (int up = 0; up < 4; up++) {
      const int s2 = sq * 4 + up;                    // pair-row index (s>>1)
      *(float2*)&xb[s2 * XP + 2 * r] = make_float2(sv[up * 2], sv[up * 2 + 1]);
    }
    if (os == 0) {
      #pragma unroll
      for (int u = 0; u < 8; u++)
        p.out[OFF_ST + ((size_t)b * Tn + t) * Sn + sq * 8 + u] = sv[u];
    }
  };

  // ---- phase E: qh = relu(h1@wprior1^T+b); ph = relu([h1,x_tn]@wpost1^T+b) ----
  auto phaseE = [&](int tn) {
    const bool dp = (tn < Tn);
    const int nch = dp ? 24 : 16;
    const float* s1 = p.h1 + (size_t)bg * BC * Hn;
    const float* slat = p.latent + (size_t)bg * BC * (size_t)(Tn * Dn) + (size_t)(dp ? tn : 0) * Dn;
    auto eload = [&](int c) -> F4x2 {
      return (c < 16) ? stLoad(s1, Hn, c * 32)
                      : stLoad(slat, (size_t)Tn * Dn, (c - 16) * 32);
    };
    float acc[32] = {};
    F4x2 nxt;
    { F4x2 cur = eload(0); nxt = eload(1); stWrite(XT(0), cur); }
    __syncthreads();
    for (int c = 0; c < nch; c++) {
      F4x2 fut;
      if (c + 2 < nch) fut = eload(c + 2);
      const float* xb = XT(c & 1);
      if (c < 16) {
        if (dp) mmE<true>(acc, xb, WQ1 + c * 32 * 4, WP1 + c * 32 * 4, rp, ks);
        else    mmE<false>(acc, xb, WQ1 + c * 32 * 4, nullptr, rp, ks);
      } else {
        mmEpost(acc, xb, WP1 + c * 32 * 4, rp, ks);
      }
      if (c + 1 < nch) stWrite(XT((c + 1) & 1), nxt);
      __syncthreads();
      nxt = fut;
    }
    bfly<32>(acc);
    if (ks < 4) {
      const int col = os * 4 + ks;
      const float bq = p.bprior1[col];
      #pragma unroll
      for (int i = 0; i < 4; i++)
        p.qh[(size_t)(bg * BC + rp * 4 + i) * Hn + col] = fmaxf(acc[i * 8 + ks] + bq, 0.f);
    } else if (ks < 8 && dp) {
      const int j = ks - 4, col = os * 4 + j;
      const float bp = p.bpost1[col];
      #pragma unroll
      for (int i = 0; i < 4; i++)
        p.ph[(size_t)(bg * BC + rp * 4 + i) * Hn + col] = fmaxf(acc[i * 8 + 4 + j] + bp, 0.f);
    }
  };

  // ---- phase B: gh0, gh1, heads ----
  auto phaseB = [&](int t) {
    {
      float acc[48] = {};
      runMM12(acc, p.h0 + (size_t)bg * BC * Hn, Hn, WH0, 16);
      bfly<48>(acc);
      writeG(GA, acc, p.bhh0);
    }
    {
      float acc[48] = {};
      runMM12(acc, p.h1 + (size_t)bg * BC * Hn, Hn, WH1, 16);
      bfly<48>(acc);
      writeG(GB, acc, p.bhh1);
    }
    if (os < 64) headPhase(t, true);
    else if (t >= 1) headPhase(t, false);
  };

  // ---- phase C: gi0 = [x_t, stoch]@wih0^T; GRU0 combine -> h0 ----
  auto phaseC = [&](int t) {
    const float* slat = p.latent + (size_t)bg * BC * (size_t)(Tn * Dn) + (size_t)t * Dn;
    const size_t ldl = (size_t)Tn * Dn;
    float acc[48] = {};
    SR sreg;
    F4x2 nxt;
    { F4x2 cur = stLoad(slat, ldl, 0); nxt = stLoad(slat, ldl, 32); stWrite(XT(0), cur); }
    __syncthreads();
    for (int c = 0; c <= 8; c++) {
      F4x2 fut;
      if (c + 2 < 8) fut = stLoad(slat, ldl, (c + 2) * 32);
      else if (c + 2 == 8) stochLoad(sreg, t);
      mm12(acc, XT(c & 1), WI0 + c * 32 * 12, rp, ks);
      if (c + 1 < 8) stWrite(XT((c + 1) & 1), nxt);
      else if (c + 1 == 8) stochWrite(XT(0), sreg, t);
      __syncthreads();
      nxt = fut;
    }
    bfly<48>(acc);
    combine(acc, GA, p.h0, p.bih0);
  };

  // ---- phase D: gi1 = h0@wih1^T; GRU1 combine -> h1 ----
  auto phaseD = [&]() {
    float acc[48] = {};
    runMM12(acc, p.h0 + (size_t)bg * BC * Hn, Hn, WI1, 16);
    bfly<48>(acc);
    combine(acc, GB, p.h1, p.bih1);
  };

  phaseE(0);
  team_bar(p, bg, grp, ++ep);

  for (int t = 0; t < Tn; t++) {
    phaseB(t);
    team_bar(p, bg, grp, ++ep);
    phaseC(t);
    team_bar(p, bg, grp, ++ep);
    phaseD();
    team_bar(p, bg, grp, ++ep);
    phaseE(t + 1);
    team_bar(p, bg, grp, ++ep);
  }

  // ---- epilogue: prior head t=255, h_final ----
  if (os >= 64) headPhase(256, false);
  {
    const int r = TID >> 2, j = TID & 3;
    const int b = bg * BC + r, col = os * 4 + j;
    p.out[OFF_HF + (size_t)b * Hn + col] = p.h0[(size_t)b * Hn + col];
    p.out[OFF_HF + (size_t)Bn * Hn + (size_t)b * Hn + col] = p.h1[(size_t)b * Hn + col];
  }
}

}  // namespace

extern "C" void kernel_launch(void* const* d_in, const int* in_sizes, int n_in,
                              void* d_out, int out_size, void* d_ws, size_t ws_size,
                              hipStream_t stream) {
  (void)in_sizes; (void)n_in; (void)out_size; (void)ws_size;
  float* ws = (float*)d_ws;
  P p;
  p.latent  = (const float*)d_in[0];
  p.hidden  = (const float*)d_in[1];
  p.eps     = (const float*)d_in[2];
  p.wih0    = (const float*)d_in[3];
  p.whh0    = (const float*)d_in[4];
  p.bih0    = (const float*)d_in[5];
  p.bhh0    = (const float*)d_in[6];
  p.wih1    = (const float*)d_in[7];
  p.whh1    = (const float*)d_in[8];
  p.bih1    = (const float*)d_in[9];
  p.bhh1    = (const float*)d_in[10];
  p.wpost1  = (const float*)d_in[11];
  p.bpost1  = (const float*)d_in[12];
  p.wpost2  = (const float*)d_in[13];
  p.bpost2  = (const float*)d_in[14];
  p.wprior1 = (const float*)d_in[15];
  p.bprior1 = (const float*)d_in[16];
  p.wprior2 = (const float*)d_in[17];
  p.bprior2 = (const float*)d_in[18];
  p.out = (float*)d_out;
  // ws layout (floats): h0 h1 ph qh ppv | barrier words
  p.h0  = ws;
  p.h1  = ws + 131072;
  p.ph  = ws + 262144;
  p.qh  = ws + 393216;
  p.ppv = ws + 524288;                 // [256][64]
  p.bars = (unsigned*)(ws + 540672);   // 20 words used

  static bool attr_done_ignored = false;
  (void)attr_done_ignored;
  (void)hipFuncSetAttribute((const void*)rssm_kernel,
                            hipFuncAttributeMaxDynamicSharedMemorySize, LDS_BYTES);

  hipMemsetAsync(p.bars, 0, 128, stream);

  void* args[] = { &p };
  hipLaunchCooperativeKernel((void*)rssm_kernel, dim3(256), dim3(512), args,
                             LDS_BYTES, stream);
}

// Round 3
// 44896.591 us; speedup vs baseline: 2.6864x; 2.6864x over previous
//
#include <hip/hip_runtime.h>
#include <math.h>

#define TID ((int)threadIdx.x)

namespace {

constexpr int Bn = 256, Tn = 256, Dn = 256, Hn = 512, Sn = 32;
constexpr int BC = 128;                 // batch rows per team
constexpr int BTS = Bn * Tn * Sn;
constexpr int OFF_ST = 0, OFF_PRM = BTS, OFF_PRLV = 2 * BTS, OFF_PM = 3 * BTS,
              OFF_PLV = 4 * BTS, OFF_HF = 5 * BTS;

// Weight LDS layouts: pair-row stride 28 floats (112B, 16B-aligned, bank-uniform),
// layout per k-pair kp: [kp*28 + c] = W[2kp][col c], [kp*28 + 12 + c] = W[2kp+1][col c].
// Head MLPs: stride 12: [kp*12 + c] (k even), [kp*12 + 4 + c] (k odd), c<4.
constexpr int oWH0 = 0;                   // whh0^T  256kp*28 = 7168
constexpr int oWH1 = oWH0 + 7168;         // whh1^T
constexpr int oWI1 = oWH1 + 7168;         // wih1^T
constexpr int oWI0 = oWI1 + 7168;         // wih0^T  144kp*28 = 4032
constexpr int oWP1 = oWI0 + 4032;         // wpost1^T 384kp*12 = 4608
constexpr int oWQ1 = oWP1 + 4608;         // wprior1^T 256kp*12 = 3072
constexpr int oWHD = oWQ1 + 3072;         // head row [512]
constexpr int oGA  = oWHD + 512;          // gh0 (+bhh0) [128][12]
constexpr int oGB  = oGA + 1536;          // gh1 (+bhh1)
constexpr int LDS_FLOATS = oGB + 1536;    // 36800 floats
constexpr int LDS_BYTES  = LDS_FLOATS * 4;  // 147200 B

struct P {
  const float *latent, *hidden, *eps;
  const float *wih0, *whh0, *bih0, *bhh0;
  const float *wih1, *whh1, *bih1, *bhh1;
  const float *wpost1, *bpost1, *wpost2, *bpost2;
  const float *wprior1, *bprior1, *wprior2, *bprior2;
  float *out;
  float *h0, *h1, *ph, *qh, *ppv;   // ws views
  unsigned *bars;                   // leaf[2][8], root[2], rel[2]
};

// ---------- two-level monotonic team barrier (128 blocks / team) ----------
__device__ __forceinline__ void team_bar(const P& p, int bg, int grp, int e) {
  __syncthreads();
  if (TID == 0) {
    unsigned* leaf = p.bars + bg * 8 + grp;
    unsigned* root = p.bars + 16 + bg;
    unsigned* rel  = p.bars + 18 + bg;
    unsigned old = __hip_atomic_fetch_add(leaf, 1u, __ATOMIC_ACQ_REL, __HIP_MEMORY_SCOPE_AGENT);
    if ((old & 15u) == 15u) {
      unsigned r = __hip_atomic_fetch_add(root, 1u, __ATOMIC_ACQ_REL, __HIP_MEMORY_SCOPE_AGENT);
      if ((r & 7u) == 7u)
        __hip_atomic_store(rel, (unsigned)e, __ATOMIC_RELEASE, __HIP_MEMORY_SCOPE_AGENT);
    }
    while (__hip_atomic_load(rel, __ATOMIC_RELAXED, __HIP_MEMORY_SCOPE_AGENT) < (unsigned)e)
      __builtin_amdgcn_s_sleep(2);
    (void)__hip_atomic_load(rel, __ATOMIC_ACQUIRE, __HIP_MEMORY_SCOPE_AGENT);
  }
  __syncthreads();
}

// ---------- weight preload (transpose into LDS, once) ----------
template<int K>
__device__ void preload12(float* wt, const float* __restrict__ W, int os) {
  constexpr int KQ = K / 4;
  for (int u = TID; u < 12 * KQ; u += 512) {
    int c = u / KQ, q = u - c * KQ;
    int row = (c >> 2) * Hn + os * 4 + (c & 3);
    float4 w = *(const float4*)(W + (size_t)row * K + q * 4);
    int kp = 2 * q;
    wt[kp * 28 + c]      = w.x; wt[kp * 28 + 12 + c] = w.y;
    wt[kp * 28 + 28 + c] = w.z; wt[kp * 28 + 40 + c] = w.w;
  }
}
template<int K>
__device__ void preload4(float* wt, const float* __restrict__ W, int os) {
  constexpr int KQ = K / 4;
  for (int u = TID; u < 4 * KQ; u += 512) {
    int c = u / KQ, q = u - c * KQ;
    int row = os * 4 + c;
    float4 w = *(const float4*)(W + (size_t)row * K + q * 4);
    int kp = 2 * q;
    wt[kp * 12 + c]      = w.x; wt[kp * 12 + 4 + c]  = w.y;
    wt[kp * 12 + 12 + c] = w.z; wt[kp * 12 + 16 + c] = w.w;
  }
}

// ---------- compute cores ----------
// 4 rows x 12 cols x 2 k: xv[i] = (x[row_i][2kp], x[row_i][2kp+1])
__device__ __forceinline__ void mm12c(float* __restrict__ acc, const float2* __restrict__ xv,
                                      const float* __restrict__ w) {
  float wA[12], wB[12];
  #pragma unroll
  for (int c = 0; c < 12; c += 4) {
    *(float4*)&wA[c] = *(const float4*)&w[c];
    *(float4*)&wB[c] = *(const float4*)&w[12 + c];
  }
  #pragma unroll
  for (int i = 0; i < 4; i++)
    #pragma unroll
    for (int c = 0; c < 12; c++)
      acc[i * 12 + c] += xv[i].x * wA[c] + xv[i].y * wB[c];
}

template<bool DP>
__device__ __forceinline__ void mmEc(float* __restrict__ acc, const float2* __restrict__ xv,
                                     const float* __restrict__ wq, const float* __restrict__ wp) {
  const float4 q0 = *(const float4*)&wq[0];
  const float4 q1 = *(const float4*)&wq[4];
  const float qA[4] = {q0.x, q0.y, q0.z, q0.w};
  const float qB[4] = {q1.x, q1.y, q1.z, q1.w};
  float pA[4] = {0, 0, 0, 0}, pB[4] = {0, 0, 0, 0};
  if (DP) {
    const float4 p0 = *(const float4*)&wp[0];
    const float4 p1 = *(const float4*)&wp[4];
    pA[0] = p0.x; pA[1] = p0.y; pA[2] = p0.z; pA[3] = p0.w;
    pB[0] = p1.x; pB[1] = p1.y; pB[2] = p1.z; pB[3] = p1.w;
  }
  #pragma unroll
  for (int i = 0; i < 4; i++)
    #pragma unroll
    for (int c = 0; c < 4; c++) {
      acc[i * 8 + c] += xv[i].x * qA[c] + xv[i].y * qB[c];
      if (DP) acc[i * 8 + 4 + c] += xv[i].x * pA[c] + xv[i].y * pB[c];
    }
}

__device__ __forceinline__ void mmEpc(float* __restrict__ acc, const float2* __restrict__ xv,
                                      const float* __restrict__ wp) {
  const float4 p0 = *(const float4*)&wp[0];
  const float4 p1 = *(const float4*)&wp[4];
  const float pA[4] = {p0.x, p0.y, p0.z, p0.w};
  const float pB[4] = {p1.x, p1.y, p1.z, p1.w};
  #pragma unroll
  for (int i = 0; i < 4; i++)
    #pragma unroll
    for (int c = 0; c < 4; c++)
      acc[i * 8 + 4 + c] += xv[i].x * pA[c] + xv[i].y * pB[c];
}

template<int N>
__device__ __forceinline__ void bfly(float* acc) {
  #pragma unroll
  for (int m = 1; m <= 8; m <<= 1)
    #pragma unroll
    for (int i = 0; i < N; i++)
      acc[i] += __shfl_xor(acc[i], m, 64);
}

__global__ __launch_bounds__(512) void rssm_kernel(P p) {
  extern __shared__ float sm[];
  const int bg = blockIdx.x & 1;        // team
  const int os = blockIdx.x >> 1;       // H-slice 0..127 (4 cols)
  const int grp = os & 7;
  const int rp = TID >> 4, ks = TID & 15;   // rp: 4-row group 0..31; ks: k-pair 0..15
  int ep = 0;

  float* WH0 = sm + oWH0; float* WH1 = sm + oWH1; float* WI1 = sm + oWI1;
  float* WI0 = sm + oWI0; float* WP1 = sm + oWP1; float* WQ1 = sm + oWQ1;
  float* WHD = sm + oWHD; float* GA = sm + oGA;  float* GB = sm + oGB;

  // ---- one-time weight preload ----
  preload12<512>(WH0, p.whh0, os);
  preload12<512>(WH1, p.whh1, os);
  preload12<512>(WI1, p.wih1, os);
  preload12<288>(WI0, p.wih0, os);
  preload4<768>(WP1, p.wpost1, os);
  preload4<512>(WQ1, p.wprior1, os);
  {
    const float* hw = (os < 64) ? (p.wpost2 + (size_t)os * Hn)
                                : (p.wprior2 + (size_t)(os - 64) * Hn);
    for (int u = TID; u < 128; u += 512)
      *(float4*)&WHD[u * 4] = *(const float4*)(hw + u * 4);
  }
  // ---- prologue: hidden -> h0/h1 (own slice) ----
  {
    const int r = TID >> 2, j = TID & 3;
    const int b = bg * BC + r, col = os * 4 + j;
    p.h0[(size_t)b * Hn + col] = p.hidden[(size_t)b * Hn + col];
    p.h1[(size_t)b * Hn + col] = p.hidden[(size_t)Bn * Hn + b * Hn + col];
  }
  team_bar(p, bg, grp, ++ep);

  // row base for this thread's 4 rows
  const int r0 = rp * 4;                 // team-local row
  const int gb0 = bg * BC + r0;          // global batch row

  // 12-col matmul over nch 32-k chunks, X rows direct from global
  auto runMM12g = [&](float* acc, const float* __restrict__ xbase, size_t ld,
                      const float* __restrict__ wt, int nch) {
    const float* xr = xbase + 2 * ks;
    #pragma unroll 4
    for (int c = 0; c < nch; c++) {
      float2 xv[4];
      #pragma unroll
      for (int i = 0; i < 4; i++)
        xv[i] = *(const float2*)(xr + (size_t)i * ld + c * 32);
      mm12c(acc, xv, wt + c * 448 + ks * 28);
    }
  };

  auto writeG = [&](float* G, const float* acc, const float* bhh) {
    if (ks < 12) {
      const int c = ks, g = c >> 2, j = c & 3;
      const float bb = bhh[g * Hn + os * 4 + j];
      #pragma unroll
      for (int i = 0; i < 4; i++) G[(r0 + i) * 12 + c] = acc[i * 12 + c] + bb;
    }
  };

  auto combine = [&](const float* acc, const float* G, float* hbuf, const float* bih) {
    if (ks < 4) {
      const int j = ks, col = os * 4 + j;
      const float b0 = bih[col], b1 = bih[Hn + col], b2 = bih[2 * Hn + col];
      #pragma unroll
      for (int i = 0; i < 4; i++) {
        const int r = r0 + i, b = bg * BC + r;
        const float gr = acc[i * 12 + j] + b0 + G[r * 12 + j];
        const float gz = acc[i * 12 + 4 + j] + b1 + G[r * 12 + 4 + j];
        const float gn = acc[i * 12 + 8 + j] + b2;
        const float hnv = G[r * 12 + 8 + j];
        const float rg = 1.f / (1.f + expf(-gr));
        const float zg = 1.f / (1.f + expf(-gz));
        const float ng = tanhf(gn + rg * hnv);
        const size_t idx = (size_t)b * Hn + col;
        hbuf[idx] = (1.f - zg) * ng + zg * hbuf[idx];
      }
    }
  };

  auto headPhase = [&](int t, bool post) {
    const int r = TID >> 2, kq = TID & 3;
    const int b = bg * BC + r;
    const float* xs = (post ? p.ph : p.qh) + (size_t)b * Hn;
    float d = 0.f;
    #pragma unroll 8
    for (int q = 0; q < 32; q++) {
      const int k = kq * 128 + q * 4;
      const float4 xvv = *(const float4*)(xs + k);
      const float4 wv = *(const float4*)&WHD[k];
      d += xvv.x * wv.x + xvv.y * wv.y + xvv.z * wv.z + xvv.w * wv.w;
    }
    d += __shfl_xor(d, 1, 64);
    d += __shfl_xor(d, 2, 64);
    if (kq == 0) {
      if (post) {
        const float val = d + p.bpost2[os];
        p.ppv[(size_t)b * 64 + os] = val;
        const size_t o = ((size_t)b * Tn + t) * Sn + (os & 31);
        p.out[(os < 32 ? OFF_PM : OFF_PLV) + o] = val;
      } else {
        const int cc = os - 64;
        const float val = d + p.bprior2[cc];
        const size_t o = ((size_t)b * Tn + (t - 1)) * Sn + (cc & 31);
        p.out[(cc < 32 ? OFF_PRM : OFF_PRLV) + o] = val;
      }
    }
  };

  // ---- phase B: gh0, gh1, heads ----
  auto phaseB = [&](int t) {
    {
      float acc[48] = {};
      runMM12g(acc, p.h0 + (size_t)gb0 * Hn, Hn, WH0, 16);
      bfly<48>(acc);
      writeG(GA, acc, p.bhh0);
    }
    {
      float acc[48] = {};
      runMM12g(acc, p.h1 + (size_t)gb0 * Hn, Hn, WH1, 16);
      bfly<48>(acc);
      writeG(GB, acc, p.bhh1);
    }
    if (os < 64) headPhase(t, true);
    else if (t >= 1) headPhase(t, false);
  };

  // ---- phase C: gi0 = [x_t, stoch]@wih0^T; GRU0 combine -> h0 ----
  auto phaseC = [&](int t) {
    float acc[48] = {};
    runMM12g(acc, p.latent + ((size_t)gb0 * Tn + t) * Dn, (size_t)Tn * Dn, WI0, 8);
    // stoch chunk (k = 256..287): compute stoch in-reg from ppv/eps
    {
      float2 sv[4];
      #pragma unroll
      for (int i = 0; i < 4; i++) {
        const int b = gb0 + i;
        const float2 pm = *(const float2*)(p.ppv + (size_t)b * 64 + 2 * ks);
        const float2 lv = *(const float2*)(p.ppv + (size_t)b * 64 + 32 + 2 * ks);
        const float2 ev = *(const float2*)(p.eps + ((size_t)b * Tn + t) * Sn + 2 * ks);
        sv[i].x = pm.x + ev.x * expf(0.5f * lv.x);
        sv[i].y = pm.y + ev.y * expf(0.5f * lv.y);
      }
      mm12c(acc, sv, WI0 + 8 * 448 + ks * 28);
      if (os == 0) {
        #pragma unroll
        for (int i = 0; i < 4; i++) {
          const int b = gb0 + i;
          *(float2*)(p.out + OFF_ST + ((size_t)b * Tn + t) * Sn + 2 * ks) = sv[i];
        }
      }
    }
    bfly<48>(acc);
    combine(acc, GA, p.h0, p.bih0);
  };

  // ---- phase D: gi1 = h0@wih1^T; GRU1 combine -> h1 ----
  auto phaseD = [&]() {
    float acc[48] = {};
    runMM12g(acc, p.h0 + (size_t)gb0 * Hn, Hn, WI1, 16);
    bfly<48>(acc);
    combine(acc, GB, p.h1, p.bih1);
  };

  // ---- phase E: qh = relu(h1@wprior1^T+b); ph = relu([h1,x_tn]@wpost1^T+b) ----
  auto phaseE = [&](int tn) {
    const bool dp = (tn < Tn);
    float acc[32] = {};
    {
      const float* xr = p.h1 + (size_t)gb0 * Hn + 2 * ks;
      #pragma unroll 4
      for (int c = 0; c < 16; c++) {
        float2 xv[4];
        #pragma unroll
        for (int i = 0; i < 4; i++)
          xv[i] = *(const float2*)(xr + (size_t)i * Hn + c * 32);
        if (dp) mmEc<true>(acc, xv, WQ1 + c * 192 + ks * 12, WP1 + c * 192 + ks * 12);
        else    mmEc<false>(acc, xv, WQ1 + c * 192 + ks * 12, nullptr);
      }
    }
    if (dp) {
      const float* xr = p.latent + ((size_t)gb0 * Tn + tn) * Dn + 2 * ks;
      #pragma unroll 4
      for (int c = 0; c < 8; c++) {
        float2 xv[4];
        #pragma unroll
        for (int i = 0; i < 4; i++)
          xv[i] = *(const float2*)(xr + (size_t)i * Tn * Dn + c * 32);
        mmEpc(acc, xv, WP1 + (16 + c) * 192 + ks * 12);
      }
    }
    bfly<32>(acc);
    if (ks < 4) {
      const int col = os * 4 + ks;
      const float bq = p.bprior1[col];
      #pragma unroll
      for (int i = 0; i < 4; i++)
        p.qh[(size_t)(gb0 + i) * Hn + col] = fmaxf(acc[i * 8 + ks] + bq, 0.f);
    } else if (ks < 8 && dp) {
      const int j = ks - 4, col = os * 4 + j;
      const float bp = p.bpost1[col];
      #pragma unroll
      for (int i = 0; i < 4; i++)
        p.ph[(size_t)(gb0 + i) * Hn + col] = fmaxf(acc[i * 8 + 4 + j] + bp, 0.f);
    }
  };

  phaseE(0);
  team_bar(p, bg, grp, ++ep);

  for (int t = 0; t < Tn; t++) {
    phaseB(t);
    team_bar(p, bg, grp, ++ep);
    phaseC(t);
    team_bar(p, bg, grp, ++ep);
    phaseD();
    team_bar(p, bg, grp, ++ep);
    phaseE(t + 1);
    team_bar(p, bg, grp, ++ep);
  }

  // ---- epilogue: prior head t=255, h_final ----
  if (os >= 64) headPhase(256, false);
  {
    const int r = TID >> 2, j = TID & 3;
    const int b = bg * BC + r, col = os * 4 + j;
    p.out[OFF_HF + (size_t)b * Hn + col] = p.h0[(size_t)b * Hn + col];
    p.out[OFF_HF + (size_t)Bn * Hn + (size_t)b * Hn + col] = p.h1[(size_t)b * Hn + col];
  }
}

}  // namespace

extern "C" void kernel_launch(void* const* d_in, const int* in_sizes, int n_in,
                              void* d_out, int out_size, void* d_ws, size_t ws_size,
                              hipStream_t stream) {
  (void)in_sizes; (void)n_in; (void)out_size; (void)ws_size;
  float* ws = (float*)d_ws;
  P p;
  p.latent  = (const float*)d_in[0];
  p.hidden  = (const float*)d_in[1];
  p.eps     = (const float*)d_in[2];
  p.wih0    = (const float*)d_in[3];
  p.whh0    = (const float*)d_in[4];
  p.bih0    = (const float*)d_in[5];
  p.bhh0    = (const float*)d_in[6];
  p.wih1    = (const float*)d_in[7];
  p.whh1    = (const float*)d_in[8];
  p.bih1    = (const float*)d_in[9];
  p.bhh1    = (const float*)d_in[10];
  p.wpost1  = (const float*)d_in[11];
  p.bpost1  = (const float*)d_in[12];
  p.wpost2  = (const float*)d_in[13];
  p.bpost2  = (const float*)d_in[14];
  p.wprior1 = (const float*)d_in[15];
  p.bprior1 = (const float*)d_in[16];
  p.wprior2 = (const float*)d_in[17];
  p.bprior2 = (const float*)d_in[18];
  p.out = (float*)d_out;
  // ws layout (floats): h0 h1 ph qh ppv | barrier words
  p.h0  = ws;
  p.h1  = ws + 131072;
  p.ph  = ws + 262144;
  p.qh  = ws + 393216;
  p.ppv = ws + 524288;                 // [256][64]
  p.bars = (unsigned*)(ws + 540672);   // 20 words used

  (void)hipFuncSetAttribute((const void*)rssm_kernel,
                            hipFuncAttributeMaxDynamicSharedMemorySize, LDS_BYTES);

  hipMemsetAsync(p.bars, 0, 128, stream);

  void* args[] = { &p };
  hipLaunchCooperativeKernel((void*)rssm_kernel, dim3(256), dim3(512), args,
                             LDS_BYTES, stream);
}

// Round 4
// 42656.256 us; speedup vs baseline: 2.8275x; 1.0525x over previous
//
#include <hip/hip_runtime.h>
#include <math.h>

#define TID ((int)threadIdx.x)

namespace {

constexpr int Bn = 256, Tn = 256, Dn = 256, Hn = 512, Sn = 32;
constexpr int BC = 128;                 // batch rows per team
constexpr int BTS = Bn * Tn * Sn;
constexpr int OFF_ST = 0, OFF_PRM = BTS, OFF_PRLV = 2 * BTS, OFF_PM = 3 * BTS,
              OFF_PLV = 4 * BTS, OFF_HF = 5 * BTS;

// Weight LDS layouts: pair-row stride 28 floats (112B, 16B-aligned, bank-uniform),
// per k-pair kp: [kp*28 + c] = W[2kp][col c], [kp*28 + 12 + c] = W[2kp+1][col c].
// Head MLPs: stride 12: [kp*12 + c] (k even), [kp*12 + 4 + c] (k odd), c<4.
constexpr int oWH0 = 0;                   // whh0^T  256kp*28 = 7168
constexpr int oWH1 = oWH0 + 7168;         // whh1^T
constexpr int oWI1 = oWH1 + 7168;         // wih1^T
constexpr int oWI0 = oWI1 + 7168;         // wih0^T  144kp*28 = 4032
constexpr int oWP1 = oWI0 + 4032;         // wpost1^T 384kp*12 = 4608
constexpr int oWQ1 = oWP1 + 4608;         // wprior1^T 256kp*12 = 3072
constexpr int oWHD = oWQ1 + 3072;         // head row [512]
constexpr int oGA  = oWHD + 512;          // gh0 (+bhh0) [128][12]
constexpr int oGB  = oGA + 1536;          // gh1 (+bhh1)
constexpr int LDS_FLOATS = oGB + 1536;    // 36800 floats
constexpr int LDS_BYTES  = LDS_FLOATS * 4;  // 147200 B

struct P {
  const float *latent, *hidden, *eps;
  const float *wih0, *whh0, *bih0, *bhh0;
  const float *wih1, *whh1, *bih1, *bhh1;
  const float *wpost1, *bpost1, *wpost2, *bpost2;
  const float *wprior1, *bprior1, *wprior2, *bprior2;
  float *out;
  float *h0, *h1, *ph, *qh, *ppv;   // ws views
  unsigned *bars;                   // leaf[2][4], root[2], rel[2]
};

// ---------- two-level monotonic team barrier (128 blocks/team, 4 XCD-local leaves) ----
__device__ __forceinline__ void team_bar(const P& p, int bg, int grp, int e) {
  __syncthreads();
  if (TID == 0) {
    unsigned* leaf = p.bars + bg * 4 + grp;
    unsigned* root = p.bars + 8 + bg;
    unsigned* rel  = p.bars + 10 + bg;
    unsigned old = __hip_atomic_fetch_add(leaf, 1u, __ATOMIC_ACQ_REL, __HIP_MEMORY_SCOPE_AGENT);
    if ((old & 31u) == 31u) {
      unsigned r = __hip_atomic_fetch_add(root, 1u, __ATOMIC_ACQ_REL, __HIP_MEMORY_SCOPE_AGENT);
      if ((r & 3u) == 3u)
        __hip_atomic_store(rel, (unsigned)e, __ATOMIC_RELEASE, __HIP_MEMORY_SCOPE_AGENT);
    }
    while (__hip_atomic_load(rel, __ATOMIC_RELAXED, __HIP_MEMORY_SCOPE_AGENT) < (unsigned)e)
      __builtin_amdgcn_s_sleep(2);
    (void)__hip_atomic_load(rel, __ATOMIC_ACQUIRE, __HIP_MEMORY_SCOPE_AGENT);
  }
  __syncthreads();
}

// ---------- weight preload (transpose into LDS, once) ----------
template<int K>
__device__ void preload12(float* wt, const float* __restrict__ W, int os) {
  constexpr int KQ = K / 4;
  for (int u = TID; u < 12 * KQ; u += 512) {
    int c = u / KQ, q = u - c * KQ;
    int row = (c >> 2) * Hn + os * 4 + (c & 3);
    float4 w = *(const float4*)(W + (size_t)row * K + q * 4);
    int kp = 2 * q;
    wt[kp * 28 + c]      = w.x; wt[kp * 28 + 12 + c] = w.y;
    wt[kp * 28 + 28 + c] = w.z; wt[kp * 28 + 40 + c] = w.w;
  }
}
template<int K>
__device__ void preload4(float* wt, const float* __restrict__ W, int os) {
  constexpr int KQ = K / 4;
  for (int u = TID; u < 4 * KQ; u += 512) {
    int c = u / KQ, q = u - c * KQ;
    int row = os * 4 + c;
    float4 w = *(const float4*)(W + (size_t)row * K + q * 4);
    int kp = 2 * q;
    wt[kp * 12 + c]      = w.x; wt[kp * 12 + 4 + c]  = w.y;
    wt[kp * 12 + 12 + c] = w.z; wt[kp * 12 + 16 + c] = w.w;
  }
}

// ---------- compute cores ----------
// 4 rows x 12 cols x 2 k
__device__ __forceinline__ void mm12c(float* __restrict__ acc, const float2* __restrict__ xv,
                                      const float* __restrict__ w) {
  float wA[12], wB[12];
  #pragma unroll
  for (int c = 0; c < 12; c += 4) {
    *(float4*)&wA[c] = *(const float4*)&w[c];
    *(float4*)&wB[c] = *(const float4*)&w[12 + c];
  }
  #pragma unroll
  for (int i = 0; i < 4; i++)
    #pragma unroll
    for (int c = 0; c < 12; c++)
      acc[i * 12 + c] += xv[i].x * wA[c] + xv[i].y * wB[c];
}

template<bool DP>
__device__ __forceinline__ void mmEc(float* __restrict__ acc, const float2* __restrict__ xv,
                                     const float* __restrict__ wq, const float* __restrict__ wp) {
  const float4 q0 = *(const float4*)&wq[0];
  const float4 q1 = *(const float4*)&wq[4];
  const float qA[4] = {q0.x, q0.y, q0.z, q0.w};
  const float qB[4] = {q1.x, q1.y, q1.z, q1.w};
  float pA[4] = {0, 0, 0, 0}, pB[4] = {0, 0, 0, 0};
  if (DP) {
    const float4 p0 = *(const float4*)&wp[0];
    const float4 p1 = *(const float4*)&wp[4];
    pA[0] = p0.x; pA[1] = p0.y; pA[2] = p0.z; pA[3] = p0.w;
    pB[0] = p1.x; pB[1] = p1.y; pB[2] = p1.z; pB[3] = p1.w;
  }
  #pragma unroll
  for (int i = 0; i < 4; i++)
    #pragma unroll
    for (int c = 0; c < 4; c++) {
      acc[i * 8 + c] += xv[i].x * qA[c] + xv[i].y * qB[c];
      if (DP) acc[i * 8 + 4 + c] += xv[i].x * pA[c] + xv[i].y * pB[c];
    }
}

__device__ __forceinline__ void mmEpc(float* __restrict__ acc, const float2* __restrict__ xv,
                                      const float* __restrict__ wp) {
  const float4 p0 = *(const float4*)&wp[0];
  const float4 p1 = *(const float4*)&wp[4];
  const float pA[4] = {p0.x, p0.y, p0.z, p0.w};
  const float pB[4] = {p1.x, p1.y, p1.z, p1.w};
  #pragma unroll
  for (int i = 0; i < 4; i++)
    #pragma unroll
    for (int c = 0; c < 4; c++)
      acc[i * 8 + 4 + c] += xv[i].x * pA[c] + xv[i].y * pB[c];
}

template<int N>
__device__ __forceinline__ void bfly(float* acc) {
  #pragma unroll
  for (int m = 1; m <= 8; m <<= 1)
    #pragma unroll
    for (int i = 0; i < N; i++)
      acc[i] += __shfl_xor(acc[i], m, 64);
}

__global__ __attribute__((amdgpu_waves_per_eu(2, 2))) __launch_bounds__(512)
void rssm_kernel(P p) {
  extern __shared__ float sm[];
  // XCD-aligned decomposition (assuming bid%8 round-robins XCDs):
  // team = bit2 of bid -> team0 on XCDs{0..3}, team1 on {4..7}; leaf = bid&3 (XCD-local).
  const int bid = blockIdx.x;
  const int bg  = (bid >> 2) & 1;
  const int grp = bid & 3;
  const int os  = ((bid >> 3) << 2) | (bid & 3);   // H-slice 0..127 (4 cols)
  const int rp = TID >> 4, ks = TID & 15;          // rp: 4-row group; ks: k-pair
  int ep = 0;

  float* WH0 = sm + oWH0; float* WH1 = sm + oWH1; float* WI1 = sm + oWI1;
  float* WI0 = sm + oWI0; float* WP1 = sm + oWP1; float* WQ1 = sm + oWQ1;
  float* WHD = sm + oWHD; float* GA = sm + oGA;  float* GB = sm + oGB;

  // ---- one-time weight preload ----
  preload12<512>(WH0, p.whh0, os);
  preload12<512>(WH1, p.whh1, os);
  preload12<512>(WI1, p.wih1, os);
  preload12<288>(WI0, p.wih0, os);
  preload4<768>(WP1, p.wpost1, os);
  preload4<512>(WQ1, p.wprior1, os);
  {
    const float* hw = (os < 64) ? (p.wpost2 + (size_t)os * Hn)
                                : (p.wprior2 + (size_t)(os - 64) * Hn);
    for (int u = TID; u < 128; u += 512)
      *(float4*)&WHD[u * 4] = *(const float4*)(hw + u * 4);
  }
  // ---- prologue: hidden -> h0/h1 (own slice) ----
  {
    const int r = TID >> 2, j = TID & 3;
    const int b = bg * BC + r, col = os * 4 + j;
    p.h0[(size_t)b * Hn + col] = p.hidden[(size_t)b * Hn + col];
    p.h1[(size_t)b * Hn + col] = p.hidden[(size_t)Bn * Hn + b * Hn + col];
  }
  team_bar(p, bg, grp, ++ep);

  const int r0 = rp * 4;                 // team-local row base
  const int gb0 = bg * BC + r0;          // global batch row base

  // 12-col matmul over nch (even) 32-k chunks; depth-2 manual pipeline, no spill.
  auto runMM12g = [&](float* acc, const float* __restrict__ xbase, size_t ld,
                      const float* __restrict__ wt, int nch) {
    const float* xr = xbase + 2 * ks;
    float2 xa[4], xb[4];
    #pragma unroll
    for (int i = 0; i < 4; i++) xa[i] = *(const float2*)(xr + (size_t)i * ld);
    #pragma unroll 1
    for (int c = 0; c < nch; c += 2) {
      #pragma unroll
      for (int i = 0; i < 4; i++)
        xb[i] = *(const float2*)(xr + (size_t)i * ld + (c + 1) * 32);
      mm12c(acc, xa, wt + c * 448 + ks * 28);
      if (c + 2 < nch) {
        #pragma unroll
        for (int i = 0; i < 4; i++)
          xa[i] = *(const float2*)(xr + (size_t)i * ld + (c + 2) * 32);
      }
      mm12c(acc, xb, wt + (c + 1) * 448 + ks * 28);
    }
  };

  auto writeG = [&](float* G, const float* acc, const float* bhh) {
    if (ks < 12) {
      const int c = ks, g = c >> 2, j = c & 3;
      const float bb = bhh[g * Hn + os * 4 + j];
      #pragma unroll
      for (int i = 0; i < 4; i++) G[(r0 + i) * 12 + c] = acc[i * 12 + c] + bb;
    }
  };

  // post-bfly: every lane holds the full sum -> lane ks<4 owns row r0+ks, writes float4.
  auto combine = [&](const float* acc, const float* G, float* hbuf, const float* bih) {
    if (ks < 4) {
      const int i = ks, r = r0 + i, b = bg * BC + r;
      const int col0 = os * 4;
      const float4 b0 = *(const float4*)(bih + col0);
      const float4 b1 = *(const float4*)(bih + Hn + col0);
      const float4 b2 = *(const float4*)(bih + 2 * Hn + col0);
      const float bb0[4] = {b0.x, b0.y, b0.z, b0.w};
      const float bb1[4] = {b1.x, b1.y, b1.z, b1.w};
      const float bb2[4] = {b2.x, b2.y, b2.z, b2.w};
      float* hp = hbuf + (size_t)b * Hn + col0;
      const float4 h4 = *(const float4*)hp;
      const float hv[4] = {h4.x, h4.y, h4.z, h4.w};
      float o[4];
      #pragma unroll
      for (int c = 0; c < 4; c++) {
        const float gr = acc[i * 12 + c]     + bb0[c] + G[r * 12 + c];
        const float gz = acc[i * 12 + 4 + c] + bb1[c] + G[r * 12 + 4 + c];
        const float gn = acc[i * 12 + 8 + c] + bb2[c];
        const float hnv = G[r * 12 + 8 + c];
        const float rg = 1.f / (1.f + expf(-gr));
        const float zg = 1.f / (1.f + expf(-gz));
        const float ng = tanhf(gn + rg * hnv);
        o[c] = (1.f - zg) * ng + zg * hv[c];
      }
      *(float4*)hp = make_float4(o[0], o[1], o[2], o[3]);
    }
  };

  auto headPhase = [&](int t, bool post) {
    const int r = TID >> 2, kq = TID & 3;
    const int b = bg * BC + r;
    const float* xs = (post ? p.ph : p.qh) + (size_t)b * Hn;
    float d = 0.f;
    #pragma unroll 8
    for (int q = 0; q < 32; q++) {
      const int k = kq * 128 + q * 4;
      const float4 xvv = *(const float4*)(xs + k);
      const float4 wv = *(const float4*)&WHD[k];
      d += xvv.x * wv.x + xvv.y * wv.y + xvv.z * wv.z + xvv.w * wv.w;
    }
    d += __shfl_xor(d, 1, 64);
    d += __shfl_xor(d, 2, 64);
    if (kq == 0) {
      if (post) {
        const float val = d + p.bpost2[os];
        p.ppv[(size_t)b * 64 + os] = val;
        const size_t o = ((size_t)b * Tn + t) * Sn + (os & 31);
        p.out[(os < 32 ? OFF_PM : OFF_PLV) + o] = val;
      } else {
        const int cc = os - 64;
        const float val = d + p.bprior2[cc];
        const size_t o = ((size_t)b * Tn + (t - 1)) * Sn + (cc & 31);
        p.out[(cc < 32 ? OFF_PRM : OFF_PRLV) + o] = val;
      }
    }
  };

  // ---- phase B: gh0, gh1, heads ----
  auto phaseB = [&](int t) {
    {
      float acc[48] = {};
      runMM12g(acc, p.h0 + (size_t)gb0 * Hn, Hn, WH0, 16);
      bfly<48>(acc);
      writeG(GA, acc, p.bhh0);
    }
    {
      float acc[48] = {};
      runMM12g(acc, p.h1 + (size_t)gb0 * Hn, Hn, WH1, 16);
      bfly<48>(acc);
      writeG(GB, acc, p.bhh1);
    }
    if (os < 64) headPhase(t, true);
    else if (t >= 1) headPhase(t, false);
  };

  // ---- phase C: gi0 = [x_t, stoch]@wih0^T; GRU0 combine -> h0 ----
  auto phaseC = [&](int t) {
    float acc[48] = {};
    // stoch inputs early (hide ppv/eps latency under the latent matmul)
    float2 sv[4];
    #pragma unroll
    for (int i = 0; i < 4; i++) {
      const int b = gb0 + i;
      const float2 pm = *(const float2*)(p.ppv + (size_t)b * 64 + 2 * ks);
      const float2 lv = *(const float2*)(p.ppv + (size_t)b * 64 + 32 + 2 * ks);
      const float2 ev = *(const float2*)(p.eps + ((size_t)b * Tn + t) * Sn + 2 * ks);
      sv[i].x = pm.x + ev.x * expf(0.5f * lv.x);
      sv[i].y = pm.y + ev.y * expf(0.5f * lv.y);
    }
    if (os == 0) {
      #pragma unroll
      for (int i = 0; i < 4; i++)
        *(float2*)(p.out + OFF_ST + ((size_t)(gb0 + i) * Tn + t) * Sn + 2 * ks) = sv[i];
    }
    runMM12g(acc, p.latent + ((size_t)gb0 * Tn + t) * Dn, (size_t)Tn * Dn, WI0, 8);
    mm12c(acc, sv, WI0 + 8 * 448 + ks * 28);
    bfly<48>(acc);
    combine(acc, GA, p.h0, p.bih0);
  };

  // ---- phase D: gi1 = h0@wih1^T; GRU1 combine -> h1 ----
  auto phaseD = [&]() {
    float acc[48] = {};
    runMM12g(acc, p.h0 + (size_t)gb0 * Hn, Hn, WI1, 16);
    bfly<48>(acc);
    combine(acc, GB, p.h1, p.bih1);
  };

  // ---- phase E: qh = relu(h1@wprior1^T+b); ph = relu([h1,x_tn]@wpost1^T+b) ----
  auto phaseE = [&](int tn) {
    const bool dp = (tn < Tn);
    float acc[32] = {};
    {
      const float* xr = p.h1 + (size_t)gb0 * Hn + 2 * ks;
      float2 xa[4], xb[4];
      #pragma unroll
      for (int i = 0; i < 4; i++) xa[i] = *(const float2*)(xr + (size_t)i * Hn);
      #pragma unroll 1
      for (int c = 0; c < 16; c += 2) {
        #pragma unroll
        for (int i = 0; i < 4; i++)
          xb[i] = *(const float2*)(xr + (size_t)i * Hn + (c + 1) * 32);
        if (dp) mmEc<true>(acc, xa, WQ1 + c * 192 + ks * 12, WP1 + c * 192 + ks * 12);
        else    mmEc<false>(acc, xa, WQ1 + c * 192 + ks * 12, nullptr);
        if (c + 2 < 16) {
          #pragma unroll
          for (int i = 0; i < 4; i++)
            xa[i] = *(const float2*)(xr + (size_t)i * Hn + (c + 2) * 32);
        }
        if (dp) mmEc<true>(acc, xb, WQ1 + (c + 1) * 192 + ks * 12, WP1 + (c + 1) * 192 + ks * 12);
        else    mmEc<false>(acc, xb, WQ1 + (c + 1) * 192 + ks * 12, nullptr);
      }
    }
    if (dp) {
      const float* xr = p.latent + ((size_t)gb0 * Tn + tn) * Dn + 2 * ks;
      const size_t ld = (size_t)Tn * Dn;
      float2 xa[4], xb[4];
      #pragma unroll
      for (int i = 0; i < 4; i++) xa[i] = *(const float2*)(xr + (size_t)i * ld);
      #pragma unroll 1
      for (int c = 0; c < 8; c += 2) {
        #pragma unroll
        for (int i = 0; i < 4; i++)
          xb[i] = *(const float2*)(xr + (size_t)i * ld + (c + 1) * 32);
        mmEpc(acc, xa, WP1 + (16 + c) * 192 + ks * 12);
        if (c + 2 < 8) {
          #pragma unroll
          for (int i = 0; i < 4; i++)
            xa[i] = *(const float2*)(xr + (size_t)i * ld + (c + 2) * 32);
        }
        mmEpc(acc, xb, WP1 + (17 + c) * 192 + ks * 12);
      }
    }
    bfly<32>(acc);
    if (ks < 4) {
      const int i = ks, b = gb0 + i;
      const float4 bq = *(const float4*)(p.bprior1 + os * 4);
      float4 q;
      q.x = fmaxf(acc[i * 8 + 0] + bq.x, 0.f);
      q.y = fmaxf(acc[i * 8 + 1] + bq.y, 0.f);
      q.z = fmaxf(acc[i * 8 + 2] + bq.z, 0.f);
      q.w = fmaxf(acc[i * 8 + 3] + bq.w, 0.f);
      *(float4*)(p.qh + (size_t)b * Hn + os * 4) = q;
    } else if (ks < 8 && dp) {
      const int i = ks - 4, b = gb0 + i;
      const float4 bp = *(const float4*)(p.bpost1 + os * 4);
      float4 v;
      v.x = fmaxf(acc[i * 8 + 4] + bp.x, 0.f);
      v.y = fmaxf(acc[i * 8 + 5] + bp.y, 0.f);
      v.z = fmaxf(acc[i * 8 + 6] + bp.z, 0.f);
      v.w = fmaxf(acc[i * 8 + 7] + bp.w, 0.f);
      *(float4*)(p.ph + (size_t)b * Hn + os * 4) = v;
    }
  };

  phaseE(0);
  team_bar(p, bg, grp, ++ep);

  for (int t = 0; t < Tn; t++) {
    phaseB(t);
    team_bar(p, bg, grp, ++ep);
    phaseC(t);
    team_bar(p, bg, grp, ++ep);
    phaseD();
    team_bar(p, bg, grp, ++ep);
    phaseE(t + 1);
    team_bar(p, bg, grp, ++ep);
  }

  // ---- epilogue: prior head t=255, h_final ----
  if (os >= 64) headPhase(256, false);
  {
    const int r = TID >> 2, j = TID & 3;
    const int b = bg * BC + r, col = os * 4 + j;
    p.out[OFF_HF + (size_t)b * Hn + col] = p.h0[(size_t)b * Hn + col];
    p.out[OFF_HF + (size_t)Bn * Hn + (size_t)b * Hn + col] = p.h1[(size_t)b * Hn + col];
  }
}

}  // namespace

extern "C" void kernel_launch(void* const* d_in, const int* in_sizes, int n_in,
                              void* d_out, int out_size, void* d_ws, size_t ws_size,
                              hipStream_t stream) {
  (void)in_sizes; (void)n_in; (void)out_size; (void)ws_size;
  float* ws = (float*)d_ws;
  P p;
  p.latent  = (const float*)d_in[0];
  p.hidden  = (const float*)d_in[1];
  p.eps     = (const float*)d_in[2];
  p.wih0    = (const float*)d_in[3];
  p.whh0    = (const float*)d_in[4];
  p.bih0    = (const float*)d_in[5];
  p.bhh0    = (const float*)d_in[6];
  p.wih1    = (const float*)d_in[7];
  p.whh1    = (const float*)d_in[8];
  p.bih1    = (const float*)d_in[9];
  p.bhh1    = (const float*)d_in[10];
  p.wpost1  = (const float*)d_in[11];
  p.bpost1  = (const float*)d_in[12];
  p.wpost2  = (const float*)d_in[13];
  p.bpost2  = (const float*)d_in[14];
  p.wprior1 = (const float*)d_in[15];
  p.bprior1 = (const float*)d_in[16];
  p.wprior2 = (const float*)d_in[17];
  p.bprior2 = (const float*)d_in[18];
  p.out = (float*)d_out;
  // ws layout (floats): h0 h1 ph qh ppv | barrier words
  p.h0  = ws;
  p.h1  = ws + 131072;
  p.ph  = ws + 262144;
  p.qh  = ws + 393216;
  p.ppv = ws + 524288;                 // [256][64]
  p.bars = (unsigned*)(ws + 540672);   // 12 words used

  (void)hipFuncSetAttribute((const void*)rssm_kernel,
                            hipFuncAttributeMaxDynamicSharedMemorySize, LDS_BYTES);

  hipMemsetAsync(p.bars, 0, 128, stream);

  void* args[] = { &p };
  hipLaunchCooperativeKernel((void*)rssm_kernel, dim3(256), dim3(512), args,
                             LDS_BYTES, stream);
}

// Round 5
// 37974.258 us; speedup vs baseline: 3.1761x; 1.1233x over previous
//
#include <hip/hip_runtime.h>
#include <math.h>

#define TID ((int)threadIdx.x)

namespace {

constexpr int Bn = 256, Tn = 256, Dn = 256, Hn = 512, Sn = 32;
constexpr int BC = 128;                 // batch rows per team
constexpr int BTS = Bn * Tn * Sn;
constexpr int OFF_ST = 0, OFF_PRM = BTS, OFF_PRLV = 2 * BTS, OFF_PM = 3 * BTS,
              OFF_PLV = 4 * BTS, OFF_HF = 5 * BTS;

// Weight LDS layouts: pair-row stride 28 floats (112B, 16B-aligned, bank-uniform),
// per k-pair kp: [kp*28 + c] = W[2kp][col c], [kp*28 + 12 + c] = W[2kp+1][col c].
// Head MLPs: stride 12: [kp*12 + c] (k even), [kp*12 + 4 + c] (k odd), c<4.
constexpr int oWH0 = 0;                   // whh0^T  256kp*28 = 7168
constexpr int oWH1 = oWH0 + 7168;         // whh1^T
constexpr int oWI1 = oWH1 + 7168;         // wih1^T
constexpr int oWI0 = oWI1 + 7168;         // wih0^T  144kp*28 = 4032
constexpr int oWP1 = oWI0 + 4032;         // wpost1^T 384kp*12 = 4608
constexpr int oWQ1 = oWP1 + 4608;         // wprior1^T 256kp*12 = 3072
constexpr int oWHD = oWQ1 + 3072;         // head row [512]
constexpr int oGA  = oWHD + 512;          // gh0 (+bhh0) [128][12]
constexpr int oGB  = oGA + 1536;          // gh1 (+bhh1)
constexpr int LDS_FLOATS = oGB + 1536;    // 36800 floats
constexpr int LDS_BYTES  = LDS_FLOATS * 4;  // 147200 B

struct P {
  const float *latent, *hidden, *eps;
  const float *wih0, *whh0, *bih0, *bhh0;
  const float *wih1, *whh1, *bih1, *bhh1;
  const float *wpost1, *bpost1, *wpost2, *bpost2;
  const float *wprior1, *bprior1, *wprior2, *bprior2;
  float *out;
  float *h0, *h1, *ph, *qh, *ppv;   // ws views
  unsigned *bars;                   // leaf[2][4], root[2], rel[2]
};

// ---------- two-level monotonic team barrier (128 blocks/team, 4 XCD-local leaves) ----
__device__ __forceinline__ void team_bar(const P& p, int bg, int grp, int e) {
  __syncthreads();
  if (TID == 0) {
    unsigned* leaf = p.bars + bg * 4 + grp;
    unsigned* root = p.bars + 8 + bg;
    unsigned* rel  = p.bars + 10 + bg;
    unsigned old = __hip_atomic_fetch_add(leaf, 1u, __ATOMIC_ACQ_REL, __HIP_MEMORY_SCOPE_AGENT);
    if ((old & 31u) == 31u) {
      unsigned r = __hip_atomic_fetch_add(root, 1u, __ATOMIC_ACQ_REL, __HIP_MEMORY_SCOPE_AGENT);
      if ((r & 3u) == 3u)
        __hip_atomic_store(rel, (unsigned)e, __ATOMIC_RELEASE, __HIP_MEMORY_SCOPE_AGENT);
    }
    while (__hip_atomic_load(rel, __ATOMIC_RELAXED, __HIP_MEMORY_SCOPE_AGENT) < (unsigned)e)
      __builtin_amdgcn_s_sleep(2);
    (void)__hip_atomic_load(rel, __ATOMIC_ACQUIRE, __HIP_MEMORY_SCOPE_AGENT);
  }
  __syncthreads();
}

// ---------- weight preload (transpose into LDS, once) ----------
template<int K>
__device__ void preload12(float* wt, const float* __restrict__ W, int os) {
  constexpr int KQ = K / 4;
  for (int u = TID; u < 12 * KQ; u += 512) {
    int c = u / KQ, q = u - c * KQ;
    int row = (c >> 2) * Hn + os * 4 + (c & 3);
    float4 w = *(const float4*)(W + (size_t)row * K + q * 4);
    int kp = 2 * q;
    wt[kp * 28 + c]      = w.x; wt[kp * 28 + 12 + c] = w.y;
    wt[kp * 28 + 28 + c] = w.z; wt[kp * 28 + 40 + c] = w.w;
  }
}
template<int K>
__device__ void preload4(float* wt, const float* __restrict__ W, int os) {
  constexpr int KQ = K / 4;
  for (int u = TID; u < 4 * KQ; u += 512) {
    int c = u / KQ, q = u - c * KQ;
    int row = os * 4 + c;
    float4 w = *(const float4*)(W + (size_t)row * K + q * 4);
    int kp = 2 * q;
    wt[kp * 12 + c]      = w.x; wt[kp * 12 + 4 + c]  = w.y;
    wt[kp * 12 + 12 + c] = w.z; wt[kp * 12 + 16 + c] = w.w;
  }
}

// ---------- compute cores ----------
// 4 rows x 12 cols x 2 k — all indices compile-time.
__device__ __forceinline__ void mm12c(float* __restrict__ acc, const float2* __restrict__ xv,
                                      const float* __restrict__ w) {
  float wA[12], wB[12];
  #pragma unroll
  for (int c = 0; c < 12; c += 4) {
    *(float4*)&wA[c] = *(const float4*)&w[c];
    *(float4*)&wB[c] = *(const float4*)&w[12 + c];
  }
  #pragma unroll
  for (int i = 0; i < 4; i++)
    #pragma unroll
    for (int c = 0; c < 12; c++)
      acc[i * 12 + c] += xv[i].x * wA[c] + xv[i].y * wB[c];
}

template<bool DP>
__device__ __forceinline__ void mmEc(float* __restrict__ acc, const float2* __restrict__ xv,
                                     const float* __restrict__ wq, const float* __restrict__ wp) {
  const float4 q0 = *(const float4*)&wq[0];
  const float4 q1 = *(const float4*)&wq[4];
  const float qA[4] = {q0.x, q0.y, q0.z, q0.w};
  const float qB[4] = {q1.x, q1.y, q1.z, q1.w};
  float pA[4] = {0, 0, 0, 0}, pB[4] = {0, 0, 0, 0};
  if (DP) {
    const float4 p0 = *(const float4*)&wp[0];
    const float4 p1 = *(const float4*)&wp[4];
    pA[0] = p0.x; pA[1] = p0.y; pA[2] = p0.z; pA[3] = p0.w;
    pB[0] = p1.x; pB[1] = p1.y; pB[2] = p1.z; pB[3] = p1.w;
  }
  #pragma unroll
  for (int i = 0; i < 4; i++)
    #pragma unroll
    for (int c = 0; c < 4; c++) {
      acc[i * 8 + c] += xv[i].x * qA[c] + xv[i].y * qB[c];
      if (DP) acc[i * 8 + 4 + c] += xv[i].x * pA[c] + xv[i].y * pB[c];
    }
}

__device__ __forceinline__ void mmEpc(float* __restrict__ acc, const float2* __restrict__ xv,
                                      const float* __restrict__ wp) {
  const float4 p0 = *(const float4*)&wp[0];
  const float4 p1 = *(const float4*)&wp[4];
  const float pA[4] = {p0.x, p0.y, p0.z, p0.w};
  const float pB[4] = {p1.x, p1.y, p1.z, p1.w};
  #pragma unroll
  for (int i = 0; i < 4; i++)
    #pragma unroll
    for (int c = 0; c < 4; c++)
      acc[i * 8 + 4 + c] += xv[i].x * pA[c] + xv[i].y * pB[c];
}

template<int N>
__device__ __forceinline__ void bfly(float* acc) {
  #pragma unroll
  for (int m = 1; m <= 8; m <<= 1)
    #pragma unroll
    for (int i = 0; i < N; i++)
      acc[i] += __shfl_xor(acc[i], m, 64);
}

__global__ __attribute__((amdgpu_waves_per_eu(2, 2))) __launch_bounds__(512)
void rssm_kernel(P p) {
  extern __shared__ float sm[];
  // XCD-aligned decomposition (assuming bid%8 round-robins XCDs):
  // team = bit2 of bid -> team0 on XCDs{0..3}, team1 on {4..7}; leaf = bid&3 (XCD-local).
  const int bid = blockIdx.x;
  const int bg  = (bid >> 2) & 1;
  const int grp = bid & 3;
  const int os  = ((bid >> 3) << 2) | (bid & 3);   // H-slice 0..127 (4 cols)
  const int rp = TID >> 4, ks = TID & 15;          // rp: 4-row group; ks: k-pair
  int ep = 0;

  float* WH0 = sm + oWH0; float* WH1 = sm + oWH1; float* WI1 = sm + oWI1;
  float* WI0 = sm + oWI0; float* WP1 = sm + oWP1; float* WQ1 = sm + oWQ1;
  float* WHD = sm + oWHD; float* GA = sm + oGA;  float* GB = sm + oGB;

  // ---- one-time weight preload ----
  preload12<512>(WH0, p.whh0, os);
  preload12<512>(WH1, p.whh1, os);
  preload12<512>(WI1, p.wih1, os);
  preload12<288>(WI0, p.wih0, os);
  preload4<768>(WP1, p.wpost1, os);
  preload4<512>(WQ1, p.wprior1, os);
  {
    const float* hw = (os < 64) ? (p.wpost2 + (size_t)os * Hn)
                                : (p.wprior2 + (size_t)(os - 64) * Hn);
    for (int u = TID; u < 128; u += 512)
      *(float4*)&WHD[u * 4] = *(const float4*)(hw + u * 4);
  }
  // ---- prologue: hidden -> h0/h1 (own slice) ----
  {
    const int r = TID >> 2, j = TID & 3;
    const int b = bg * BC + r, col = os * 4 + j;
    p.h0[(size_t)b * Hn + col] = p.hidden[(size_t)b * Hn + col];
    p.h1[(size_t)b * Hn + col] = p.hidden[(size_t)Bn * Hn + b * Hn + col];
  }
  team_bar(p, bg, grp, ++ep);

  const int r0 = rp * 4;                 // team-local row base
  const int gb0 = bg * BC + r0;          // global batch row base

  // 12-col matmul over nch (even) 32-k chunks; depth-2 manual pipeline.
  auto runMM12g = [&](float* acc, const float* __restrict__ xbase, size_t ld,
                      const float* __restrict__ wt, int nch) {
    const float* xr = xbase + 2 * ks;
    float2 xa[4], xb[4];
    #pragma unroll
    for (int i = 0; i < 4; i++) xa[i] = *(const float2*)(xr + (size_t)i * ld);
    #pragma unroll 1
    for (int c = 0; c < nch; c += 2) {
      #pragma unroll
      for (int i = 0; i < 4; i++)
        xb[i] = *(const float2*)(xr + (size_t)i * ld + (c + 1) * 32);
      mm12c(acc, xa, wt + c * 448 + ks * 28);
      if (c + 2 < nch) {
        #pragma unroll
        for (int i = 0; i < 4; i++)
          xa[i] = *(const float2*)(xr + (size_t)i * ld + (c + 2) * 32);
      }
      mm12c(acc, xb, wt + (c + 1) * 448 + ks * 28);
    }
  };

  // All acc indices COMPILE-TIME (rule #20): predicated static loops, never acc[runtime].
  auto writeG = [&](float* G, const float* acc, const float* bhh) {
    #pragma unroll
    for (int c = 0; c < 12; c++) {
      if (ks == c) {
        const int g = c >> 2, j = c & 3;
        const float bb = bhh[g * Hn + os * 4 + j];
        #pragma unroll
        for (int i = 0; i < 4; i++) G[(r0 + i) * 12 + c] = acc[i * 12 + c] + bb;
      }
    }
  };

  // post-bfly: every lane holds the full sum -> lane ks==i owns row r0+i, writes float4.
  auto combine = [&](const float* acc, const float* G, float* hbuf, const float* bih) {
    const int col0 = os * 4;
    #pragma unroll
    for (int i = 0; i < 4; i++) {
      if (ks == i) {
        const int r = r0 + i, b = bg * BC + r;
        const float4 b0 = *(const float4*)(bih + col0);
        const float4 b1 = *(const float4*)(bih + Hn + col0);
        const float4 b2 = *(const float4*)(bih + 2 * Hn + col0);
        const float bb0[4] = {b0.x, b0.y, b0.z, b0.w};
        const float bb1[4] = {b1.x, b1.y, b1.z, b1.w};
        const float bb2[4] = {b2.x, b2.y, b2.z, b2.w};
        float* hp = hbuf + (size_t)b * Hn + col0;
        const float4 h4 = *(const float4*)hp;
        const float hv[4] = {h4.x, h4.y, h4.z, h4.w};
        float o[4];
        #pragma unroll
        for (int c = 0; c < 4; c++) {
          const float gr = acc[i * 12 + c]     + bb0[c] + G[r * 12 + c];
          const float gz = acc[i * 12 + 4 + c] + bb1[c] + G[r * 12 + 4 + c];
          const float gn = acc[i * 12 + 8 + c] + bb2[c];
          const float hnv = G[r * 12 + 8 + c];
          const float rg = 1.f / (1.f + expf(-gr));
          const float zg = 1.f / (1.f + expf(-gz));
          const float ng = tanhf(gn + rg * hnv);
          o[c] = (1.f - zg) * ng + zg * hv[c];
        }
        *(float4*)hp = make_float4(o[0], o[1], o[2], o[3]);
      }
    }
  };

  auto headPhase = [&](int t, bool post) {
    const int r = TID >> 2, kq = TID & 3;
    const int b = bg * BC + r;
    const float* xs = (post ? p.ph : p.qh) + (size_t)b * Hn;
    float d = 0.f;
    #pragma unroll 8
    for (int q = 0; q < 32; q++) {
      const int k = kq * 128 + q * 4;
      const float4 xvv = *(const float4*)(xs + k);
      const float4 wv = *(const float4*)&WHD[k];
      d += xvv.x * wv.x + xvv.y * wv.y + xvv.z * wv.z + xvv.w * wv.w;
    }
    d += __shfl_xor(d, 1, 64);
    d += __shfl_xor(d, 2, 64);
    if (kq == 0) {
      if (post) {
        const float val = d + p.bpost2[os];
        p.ppv[(size_t)b * 64 + os] = val;
        const size_t o = ((size_t)b * Tn + t) * Sn + (os & 31);
        p.out[(os < 32 ? OFF_PM : OFF_PLV) + o] = val;
      } else {
        const int cc = os - 64;
        const float val = d + p.bprior2[cc];
        const size_t o = ((size_t)b * Tn + (t - 1)) * Sn + (cc & 31);
        p.out[(cc < 32 ? OFF_PRM : OFF_PRLV) + o] = val;
      }
    }
  };

  // ---- phase B: gh0, gh1, heads ----
  auto phaseB = [&](int t) {
    {
      float acc[48] = {};
      runMM12g(acc, p.h0 + (size_t)gb0 * Hn, Hn, WH0, 16);
      bfly<48>(acc);
      writeG(GA, acc, p.bhh0);
    }
    {
      float acc[48] = {};
      runMM12g(acc, p.h1 + (size_t)gb0 * Hn, Hn, WH1, 16);
      bfly<48>(acc);
      writeG(GB, acc, p.bhh1);
    }
    if (os < 64) headPhase(t, true);
    else if (t >= 1) headPhase(t, false);
  };

  // ---- phase C: gi0 = [x_t, stoch]@wih0^T; GRU0 combine -> h0 ----
  auto phaseC = [&](int t) {
    float acc[48] = {};
    // stoch inputs early (hide ppv/eps latency under the latent matmul)
    float2 sv[4];
    #pragma unroll
    for (int i = 0; i < 4; i++) {
      const int b = gb0 + i;
      const float2 pm = *(const float2*)(p.ppv + (size_t)b * 64 + 2 * ks);
      const float2 lv = *(const float2*)(p.ppv + (size_t)b * 64 + 32 + 2 * ks);
      const float2 ev = *(const float2*)(p.eps + ((size_t)b * Tn + t) * Sn + 2 * ks);
      sv[i].x = pm.x + ev.x * expf(0.5f * lv.x);
      sv[i].y = pm.y + ev.y * expf(0.5f * lv.y);
    }
    if (os == 0) {
      #pragma unroll
      for (int i = 0; i < 4; i++)
        *(float2*)(p.out + OFF_ST + ((size_t)(gb0 + i) * Tn + t) * Sn + 2 * ks) = sv[i];
    }
    runMM12g(acc, p.latent + ((size_t)gb0 * Tn + t) * Dn, (size_t)Tn * Dn, WI0, 8);
    mm12c(acc, sv, WI0 + 8 * 448 + ks * 28);
    bfly<48>(acc);
    combine(acc, GA, p.h0, p.bih0);
  };

  // ---- phase D: gi1 = h0@wih1^T; GRU1 combine -> h1 ----
  auto phaseD = [&]() {
    float acc[48] = {};
    runMM12g(acc, p.h0 + (size_t)gb0 * Hn, Hn, WI1, 16);
    bfly<48>(acc);
    combine(acc, GB, p.h1, p.bih1);
  };

  // ---- phase E: qh = relu(h1@wprior1^T+b); ph = relu([h1,x_tn]@wpost1^T+b) ----
  auto phaseE = [&](int tn) {
    const bool dp = (tn < Tn);
    float acc[32] = {};
    {
      const float* xr = p.h1 + (size_t)gb0 * Hn + 2 * ks;
      float2 xa[4], xb[4];
      #pragma unroll
      for (int i = 0; i < 4; i++) xa[i] = *(const float2*)(xr + (size_t)i * Hn);
      #pragma unroll 1
      for (int c = 0; c < 16; c += 2) {
        #pragma unroll
        for (int i = 0; i < 4; i++)
          xb[i] = *(const float2*)(xr + (size_t)i * Hn + (c + 1) * 32);
        if (dp) mmEc<true>(acc, xa, WQ1 + c * 192 + ks * 12, WP1 + c * 192 + ks * 12);
        else    mmEc<false>(acc, xa, WQ1 + c * 192 + ks * 12, nullptr);
        if (c + 2 < 16) {
          #pragma unroll
          for (int i = 0; i < 4; i++)
            xa[i] = *(const float2*)(xr + (size_t)i * Hn + (c + 2) * 32);
        }
        if (dp) mmEc<true>(acc, xb, WQ1 + (c + 1) * 192 + ks * 12, WP1 + (c + 1) * 192 + ks * 12);
        else    mmEc<false>(acc, xb, WQ1 + (c + 1) * 192 + ks * 12, nullptr);
      }
    }
    if (dp) {
      const float* xr = p.latent + ((size_t)gb0 * Tn + tn) * Dn + 2 * ks;
      const size_t ld = (size_t)Tn * Dn;
      float2 xa[4], xb[4];
      #pragma unroll
      for (int i = 0; i < 4; i++) xa[i] = *(const float2*)(xr + (size_t)i * ld);
      #pragma unroll 1
      for (int c = 0; c < 8; c += 2) {
        #pragma unroll
        for (int i = 0; i < 4; i++)
          xb[i] = *(const float2*)(xr + (size_t)i * ld + (c + 1) * 32);
        mmEpc(acc, xa, WP1 + (16 + c) * 192 + ks * 12);
        if (c + 2 < 8) {
          #pragma unroll
          for (int i = 0; i < 4; i++)
            xa[i] = *(const float2*)(xr + (size_t)i * ld + (c + 2) * 32);
        }
        mmEpc(acc, xb, WP1 + (17 + c) * 192 + ks * 12);
      }
    }
    bfly<32>(acc);
    const int col0 = os * 4;
    #pragma unroll
    for (int i = 0; i < 4; i++) {
      if (ks == i) {
        const int b = gb0 + i;
        const float4 bq = *(const float4*)(p.bprior1 + col0);
        float4 q;
        q.x = fmaxf(acc[i * 8 + 0] + bq.x, 0.f);
        q.y = fmaxf(acc[i * 8 + 1] + bq.y, 0.f);
        q.z = fmaxf(acc[i * 8 + 2] + bq.z, 0.f);
        q.w = fmaxf(acc[i * 8 + 3] + bq.w, 0.f);
        *(float4*)(p.qh + (size_t)b * Hn + col0) = q;
      }
    }
    if (dp) {
      #pragma unroll
      for (int i = 0; i < 4; i++) {
        if (ks == i + 4) {
          const int b = gb0 + i;
          const float4 bp = *(const float4*)(p.bpost1 + col0);
          float4 v;
          v.x = fmaxf(acc[i * 8 + 4] + bp.x, 0.f);
          v.y = fmaxf(acc[i * 8 + 5] + bp.y, 0.f);
          v.z = fmaxf(acc[i * 8 + 6] + bp.z, 0.f);
          v.w = fmaxf(acc[i * 8 + 7] + bp.w, 0.f);
          *(float4*)(p.ph + (size_t)b * Hn + col0) = v;
        }
      }
    }
  };

  phaseE(0);
  team_bar(p, bg, grp, ++ep);

  for (int t = 0; t < Tn; t++) {
    phaseB(t);
    team_bar(p, bg, grp, ++ep);
    phaseC(t);
    team_bar(p, bg, grp, ++ep);
    phaseD();
    team_bar(p, bg, grp, ++ep);
    phaseE(t + 1);
    team_bar(p, bg, grp, ++ep);
  }

  // ---- epilogue: prior head t=255, h_final ----
  if (os >= 64) headPhase(256, false);
  {
    const int r = TID >> 2, j = TID & 3;
    const int b = bg * BC + r, col = os * 4 + j;
    p.out[OFF_HF + (size_t)b * Hn + col] = p.h0[(size_t)b * Hn + col];
    p.out[OFF_HF + (size_t)Bn * Hn + (size_t)b * Hn + col] = p.h1[(size_t)b * Hn + col];
  }
}

}  // namespace

extern "C" void kernel_launch(void* const* d_in, const int* in_sizes, int n_in,
                              void* d_out, int out_size, void* d_ws, size_t ws_size,
                              hipStream_t stream) {
  (void)in_sizes; (void)n_in; (void)out_size; (void)ws_size;
  float* ws = (float*)d_ws;
  P p;
  p.latent  = (const float*)d_in[0];
  p.hidden  = (const float*)d_in[1];
  p.eps     = (const float*)d_in[2];
  p.wih0    = (const float*)d_in[3];
  p.whh0    = (const float*)d_in[4];
  p.bih0    = (const float*)d_in[5];
  p.bhh0    = (const float*)d_in[6];
  p.wih1    = (const float*)d_in[7];
  p.whh1    = (const float*)d_in[8];
  p.bih1    = (const float*)d_in[9];
  p.bhh1    = (const float*)d_in[10];
  p.wpost1  = (const float*)d_in[11];
  p.bpost1  = (const float*)d_in[12];
  p.wpost2  = (const float*)d_in[13];
  p.bpost2  = (const float*)d_in[14];
  p.wprior1 = (const float*)d_in[15];
  p.bprior1 = (const float*)d_in[16];
  p.wprior2 = (const float*)d_in[17];
  p.bprior2 = (const float*)d_in[18];
  p.out = (float*)d_out;
  // ws layout (floats): h0 h1 ph qh ppv | barrier words
  p.h0  = ws;
  p.h1  = ws + 131072;
  p.ph  = ws + 262144;
  p.qh  = ws + 393216;
  p.ppv = ws + 524288;                 // [256][64]
  p.bars = (unsigned*)(ws + 540672);   // 12 words used

  (void)hipFuncSetAttribute((const void*)rssm_kernel,
                            hipFuncAttributeMaxDynamicSharedMemorySize, LDS_BYTES);

  hipMemsetAsync(p.bars, 0, 128, stream);

  void* args[] = { &p };
  hipLaunchCooperativeKernel((void*)rssm_kernel, dim3(256), dim3(512), args,
                             LDS_BYTES, stream);
}